// Round 2
// baseline (1223.474 us; speedup 1.0000x reference)
//
#include <hip/hip_runtime.h>
#include <math.h>

// B=8, Cin=512, H=W=64, Ci=128, Cq=16, recurrence=2. fp32 in/out.
// 3x3 convs via split-bf16 MFMA (Wh*Xh + Wh*Xl + Wl*Xh), cc module fp32 vector.

typedef __attribute__((ext_vector_type(8))) short short8;   // 8 bf16 (4 VGPR)
typedef __attribute__((ext_vector_type(4))) float f32x4;

__device__ __forceinline__ unsigned short f2bf(float x) {
    unsigned u = __float_as_uint(x);
    unsigned r = u + 0x7FFFu + ((u >> 16) & 1u);
    return (unsigned short)(r >> 16);
}
__device__ __forceinline__ float bf2f(unsigned short h) {
    return __uint_as_float(((unsigned)h) << 16);
}

// ---------------- prep: fold BN into scale/shift ----------------
__global__ __launch_bounds__(256) void prep_bn_kernel(
        const float* g1, const float* b1, const float* m1, const float* v1,
        const float* g2, const float* b2, const float* m2, const float* v2,
        float* s1o, float* h1o, float* s2o, float* h2o) {
    int t = threadIdx.x;
    if (t < 128) {
        float s = g1[t] * __frsqrt_rn(v1[t] + 1e-5f);
        s1o[t] = s; h1o[t] = b1[t] - m1[t] * s;
    } else {
        int c = t - 128;
        float s = g2[c] * __frsqrt_rn(v2[c] + 1e-5f);
        s2o[c] = s; h2o[c] = b2[c] - m2[c] * s;
    }
}

// ---------------- prep: conv weights -> bf16 hi/lo, layout [tap][cout][ci] ----------------
__global__ __launch_bounds__(256) void prep_w_kernel(
        const float* __restrict__ w, unsigned short* __restrict__ WH,
        unsigned short* __restrict__ WL, int CIN, int COUT) {
    int idx = blockIdx.x * 256 + threadIdx.x;
    if (idx >= COUT * CIN) return;
    int cout = idx / CIN, ci = idx - cout * CIN;
    #pragma unroll
    for (int tap = 0; tap < 9; ++tap) {
        float v = w[(size_t)idx * 9 + tap];
        unsigned short h = f2bf(v);
        unsigned short l = f2bf(v - bf2f(h));
        size_t o = ((size_t)tap * COUT + cout) * CIN + ci;
        WH[o] = h; WL[o] = l;
    }
}

// ---------------- prep: transpose 1x1-conv weights ----------------
__global__ __launch_bounds__(256) void prep_qkv_kernel(
        const float* __restrict__ wq, const float* __restrict__ wk,
        const float* __restrict__ wv,
        float* __restrict__ wqk_t, float* __restrict__ wv_t) {
    int e = blockIdx.x * 256 + threadIdx.x;
    if (e < 4096) {
        int ci = e >> 5, co = e & 31;
        wqk_t[e] = (co < 16) ? wq[co * 128 + ci] : wk[(co - 16) * 128 + ci];
    } else if (e < 4096 + 16384) {
        int e2 = e - 4096;
        int ci = e2 >> 7, co = e2 & 127;
        wv_t[e2] = wv[co * 128 + ci];
    }
}

// ---------------- NCHW fp32 -> chunked channels-last [b][chunk][h][w][32] ----------------
__global__ __launch_bounds__(256) void transpose_cl_kernel(
        const float* __restrict__ in, float* __restrict__ out, int NCH) {
    __shared__ float T[32][260];               // [ci][hh*65 + w]
    const int t = threadIdx.x;
    const int h0 = blockIdx.x * 4, b = blockIdx.y, ck = blockIdx.z;
    const float* base = in + (size_t)(b * NCH + ck) * 32 * 4096;
    const int ci = t >> 3, w0 = (t & 7) * 8;
    #pragma unroll
    for (int hh = 0; hh < 4; ++hh) {
        float4 u0 = *(const float4*)&base[(size_t)ci * 4096 + (h0 + hh) * 64 + w0];
        float4 u1 = *(const float4*)&base[(size_t)ci * 4096 + (h0 + hh) * 64 + w0 + 4];
        T[ci][hh * 65 + w0 + 0] = u0.x; T[ci][hh * 65 + w0 + 1] = u0.y;
        T[ci][hh * 65 + w0 + 2] = u0.z; T[ci][hh * 65 + w0 + 3] = u0.w;
        T[ci][hh * 65 + w0 + 4] = u1.x; T[ci][hh * 65 + w0 + 5] = u1.y;
        T[ci][hh * 65 + w0 + 6] = u1.z; T[ci][hh * 65 + w0 + 7] = u1.w;
    }
    __syncthreads();
    const int w = t & 63, hh2 = t >> 6;
    float* op = out + ((size_t)((b * NCH + ck) * 4096) + (h0 + hh2) * 64 + w) * 32;
    #pragma unroll
    for (int cg = 0; cg < 8; ++cg) {
        float4 r;
        r.x = T[cg * 4 + 0][hh2 * 65 + w];
        r.y = T[cg * 4 + 1][hh2 * 65 + w];
        r.z = T[cg * 4 + 2][hh2 * 65 + w];
        r.w = T[cg * 4 + 3][hh2 * 65 + w];
        *(float4*)&op[cg * 4] = r;
    }
}

// ---------------- 3x3 conv via split-bf16 MFMA ----------------
// Block: 64 cout x 2 rows x 64 w; 4 waves = (cout-half) x (row o).
// Wave: 2 m-tiles(16 cout) x 4 n-tiles(16 w). K-chunk = 32 ci at fixed tap.
// EPI: 0 = BN scale/shift, 1 = ELU(512).
template<int NCHUNK, int COUT, int EPI, int C1CH>
__global__ __launch_bounds__(256, 2) void conv3x3_mfma_kernel(
        const float* __restrict__ xt1, const float* __restrict__ xt2,
        const unsigned short* __restrict__ WH, const unsigned short* __restrict__ WL,
        const float* __restrict__ bns, const float* __restrict__ bnb,
        float* __restrict__ out) {
    constexpr int CINF = NCHUNK * 32;
    __shared__ unsigned short XS[2][4][66][40];   // [hl][row][1+w][ci], pad 40
    __shared__ unsigned short WAs[2][64][104];    // [hl][cout][kw*32+ci], pad 104
    const int t = threadIdx.x;
    const int lane = t & 63, wave = t >> 6;
    const int ch = wave >> 1, o = wave & 1;       // cout-half, row-offset
    const int ln = lane & 15, lg = lane >> 4;
    const int h0 = blockIdx.x * 2, b = blockIdx.y, cb0 = blockIdx.z * 64;

    // zero the w = -1 / w = 64 pads once (never overwritten later)
    if (t < 32) {
        int r = t >> 3, s = (t >> 2) & 1, cig = t & 3;
        short8 z = {};
        *(short8*)&XS[0][r][s * 65][cig * 8] = z;
        *(short8*)&XS[1][r][s * 65][cig * 8] = z;
    }

    f32x4 acc[2][4];
    #pragma unroll
    for (int mi = 0; mi < 2; ++mi)
        #pragma unroll
        for (int q = 0; q < 4; ++q) acc[mi][q] = (f32x4){0.f, 0.f, 0.f, 0.f};

    const int xr = t >> 6, xw = t & 63;           // X-stage role: (row, w)
    for (int chunk = 0; chunk < NCHUNK; ++chunk) {
        const float* src = (chunk < C1CH)
            ? xt1 + (size_t)(b * C1CH + chunk) * 4096 * 32
            : xt2 + (size_t)(b * (NCHUNK - C1CH) + (chunk - C1CH)) * 4096 * 32;
        // stage X: 4 rows x 64 w x 32 ci, split to hi/lo
        {
            int row = h0 - 1 + xr;
            if (row >= 0 && row < 64) {
                const float* sp = src + ((size_t)row * 64 + xw) * 32;
                #pragma unroll
                for (int cg = 0; cg < 4; ++cg) {
                    float4 u0 = *(const float4*)&sp[cg * 8];
                    float4 u1 = *(const float4*)&sp[cg * 8 + 4];
                    float xv[8] = {u0.x, u0.y, u0.z, u0.w, u1.x, u1.y, u1.z, u1.w};
                    short8 hi, lo;
                    #pragma unroll
                    for (int j = 0; j < 8; ++j) {
                        unsigned short hb = f2bf(xv[j]);
                        hi[j] = (short)hb;
                        lo[j] = (short)f2bf(xv[j] - bf2f(hb));
                    }
                    *(short8*)&XS[0][xr][1 + xw][cg * 8] = hi;
                    *(short8*)&XS[1][xr][1 + xw][cg * 8] = lo;
                }
            } else {
                short8 z = {};
                #pragma unroll
                for (int cg = 0; cg < 4; ++cg) {
                    *(short8*)&XS[0][xr][1 + xw][cg * 8] = z;
                    *(short8*)&XS[1][xr][1 + xw][cg * 8] = z;
                }
            }
        }
        const int ci0 = chunk * 32;
        for (int kh = 0; kh < 3; ++kh) {
            // stage W for taps kh*3..kh*3+2: 64 cout x 3 kw x 32 ci, hi+lo
            #pragma unroll
            for (int i = 0; i < 3; ++i) {
                int e = t + i * 256;               // e < 768
                int cout = e / 12, r2 = e - cout * 12;
                int kw = r2 >> 2, cig = r2 & 3;
                size_t go = ((size_t)(kh * 3 + kw) * COUT + cb0 + cout) * CINF + ci0 + cig * 8;
                *(short8*)&WAs[0][cout][kw * 32 + cig * 8] = *(const short8*)&WH[go];
                *(short8*)&WAs[1][cout][kw * 32 + cig * 8] = *(const short8*)&WL[go];
            }
            __syncthreads();
            const int row = o + kh;
            #pragma unroll
            for (int kw = 0; kw < 3; ++kw) {
                short8 ah0 = *(const short8*)&WAs[0][ch * 32 + ln][kw * 32 + lg * 8];
                short8 ah1 = *(const short8*)&WAs[0][ch * 32 + 16 + ln][kw * 32 + lg * 8];
                short8 al0 = *(const short8*)&WAs[1][ch * 32 + ln][kw * 32 + lg * 8];
                short8 al1 = *(const short8*)&WAs[1][ch * 32 + 16 + ln][kw * 32 + lg * 8];
                #pragma unroll
                for (int q = 0; q < 4; ++q) {
                    short8 bh = *(const short8*)&XS[0][row][q * 16 + ln + kw][lg * 8];
                    short8 bl = *(const short8*)&XS[1][row][q * 16 + ln + kw][lg * 8];
                    acc[0][q] = __builtin_amdgcn_mfma_f32_16x16x32_bf16(ah0, bh, acc[0][q], 0, 0, 0);
                    acc[1][q] = __builtin_amdgcn_mfma_f32_16x16x32_bf16(ah1, bh, acc[1][q], 0, 0, 0);
                    acc[0][q] = __builtin_amdgcn_mfma_f32_16x16x32_bf16(ah0, bl, acc[0][q], 0, 0, 0);
                    acc[1][q] = __builtin_amdgcn_mfma_f32_16x16x32_bf16(ah1, bl, acc[1][q], 0, 0, 0);
                    acc[0][q] = __builtin_amdgcn_mfma_f32_16x16x32_bf16(al0, bh, acc[0][q], 0, 0, 0);
                    acc[1][q] = __builtin_amdgcn_mfma_f32_16x16x32_bf16(al1, bh, acc[1][q], 0, 0, 0);
                }
            }
            __syncthreads();
        }
    }
    // epilogue: C-frag col = lane&15 -> w, row = (lane>>4)*4+reg -> cout (m89-verified)
    const int hh = h0 + o;
    #pragma unroll
    for (int mi = 0; mi < 2; ++mi) {
        #pragma unroll
        for (int q = 0; q < 4; ++q) {
            #pragma unroll
            for (int reg = 0; reg < 4; ++reg) {
                int cout = cb0 + ch * 32 + mi * 16 + lg * 4 + reg;
                int wv2 = q * 16 + ln;
                float val = acc[mi][q][reg];
                if (EPI == 0) val = val * bns[cout] + bnb[cout];
                else          val = (val > 0.f) ? val : 512.0f * expm1f(val);
                out[((size_t)(b * COUT + cout) * 64 + hh) * 64 + wv2] = val;
            }
        }
    }
}

// ================= cc_module kernels (fp32 vector, unchanged from round 0) =================
__global__ __launch_bounds__(256) void qk_kernel(
        const float* __restrict__ X, const float* __restrict__ wqk_t,
        const float* __restrict__ bq, const float* __restrict__ bk,
        float* __restrict__ q, float* __restrict__ k) {
    __shared__ float xls[128][64];
    __shared__ float wls[128][32];
    const int t = threadIdx.x;
    const int h = blockIdx.x, b = blockIdx.y;
    const float* xb = X + (size_t)b * 128 * 4096 + (size_t)h * 64;
    #pragma unroll
    for (int i = 0; i < 32; ++i) {
        int e = t + i * 256;
        xls[e >> 6][e & 63] = xb[(size_t)(e >> 6) * 4096 + (e & 63)];
    }
    #pragma unroll
    for (int i = 0; i < 16; ++i) {
        int e = t + i * 256;
        wls[e >> 5][e & 31] = wqk_t[e];
    }
    __syncthreads();
    const int w = t & 63, g = t >> 6;
    const int co0 = g * 8;
    float acc[8];
    #pragma unroll
    for (int c = 0; c < 8; ++c) acc[c] = 0.f;
    #pragma unroll 8
    for (int ci = 0; ci < 128; ++ci) {
        float xv = xls[ci][w];
        float4 wa = *(const float4*)&wls[ci][co0];
        float4 wb = *(const float4*)&wls[ci][co0 + 4];
        const float* pa = (const float*)&wa;
        const float* pb = (const float*)&wb;
        #pragma unroll
        for (int c = 0; c < 4; ++c) { acc[c] += pa[c] * xv; acc[4 + c] += pb[c] * xv; }
    }
    #pragma unroll
    for (int c = 0; c < 8; ++c) {
        int co = co0 + c;
        if (co < 16) q[((size_t)(b * 16 + co) * 64 + h) * 64 + w]      = acc[c] + bq[co];
        else         k[((size_t)(b * 16 + co - 16) * 64 + h) * 64 + w] = acc[c] + bk[co - 16];
    }
}

__global__ __launch_bounds__(256) void v_kernel(
        const float* __restrict__ X, const float* __restrict__ wv_t,
        const float* __restrict__ bv, float* __restrict__ v) {
    __shared__ float xls[16][64];
    __shared__ float wls[16][128];
    const int t = threadIdx.x;
    const int n0 = blockIdx.x * 64, b = blockIdx.y;
    const int wt = t & 15, ct = t >> 4;
    const float* xb = X + (size_t)b * 128 * 4096;
    float acc[8][4] = {};
    for (int ci0 = 0; ci0 < 128; ci0 += 16) {
        #pragma unroll
        for (int i = 0; i < 4; ++i) {
            int e = t + i * 256;
            xls[e >> 6][e & 63] = xb[(size_t)(ci0 + (e >> 6)) * 4096 + n0 + (e & 63)];
        }
        #pragma unroll
        for (int i = 0; i < 8; ++i) {
            int e = t + i * 256;
            wls[e >> 7][e & 127] = wv_t[(size_t)(ci0 + (e >> 7)) * 128 + (e & 127)];
        }
        __syncthreads();
        #pragma unroll 4
        for (int ci = 0; ci < 16; ++ci) {
            float4 xv = *(const float4*)&xls[ci][wt * 4];
            float4 wa = *(const float4*)&wls[ci][ct * 8];
            float4 wb = *(const float4*)&wls[ci][ct * 8 + 4];
            const float* px = (const float*)&xv;
            const float* pa = (const float*)&wa;
            const float* pb = (const float*)&wb;
            #pragma unroll
            for (int j = 0; j < 4; ++j)
                #pragma unroll
                for (int c = 0; c < 4; ++c) {
                    acc[c][j]     += pa[c] * px[j];
                    acc[4 + c][j] += pb[c] * px[j];
                }
        }
        __syncthreads();
    }
    #pragma unroll
    for (int c = 0; c < 8; ++c) {
        int co = ct * 8 + c;
        float bb = bv[co];
        float4 r = {acc[c][0] + bb, acc[c][1] + bb, acc[c][2] + bb, acc[c][3] + bb};
        *(float4*)&v[(size_t)(b * 128 + co) * 4096 + n0 + wt * 4] = r;
    }
}

__global__ __launch_bounds__(256) void eh_kernel(
        const float* __restrict__ q, const float* __restrict__ k,
        float* __restrict__ att) {
    __shared__ float qs[16][64];
    __shared__ float ks[16][64];
    const int t = threadIdx.x;
    const int w = blockIdx.x, b = blockIdx.y;
    #pragma unroll
    for (int i = 0; i < 4; ++i) {
        int e = t + i * 256;
        int c = e >> 6, h = e & 63;
        size_t idx = ((size_t)(b * 16 + c) * 64 + h) * 64 + w;
        qs[c][h] = q[idx];
        ks[c][h] = k[idx];
    }
    __syncthreads();
    const int g0 = (t & 15) * 4, h0 = (t >> 4) * 4;
    float acc[4][4] = {};
    #pragma unroll
    for (int c = 0; c < 16; ++c) {
        float4 qv = *(const float4*)&qs[c][h0];
        float4 kv = *(const float4*)&ks[c][g0];
        const float* pq = (const float*)&qv;
        const float* pk = (const float*)&kv;
        #pragma unroll
        for (int i = 0; i < 4; ++i)
            #pragma unroll
            for (int j = 0; j < 4; ++j) acc[i][j] += pq[i] * pk[j];
    }
    #pragma unroll
    for (int i = 0; i < 4; ++i) {
        int h = h0 + i;
        int dj = h - g0;
        if (dj >= 0 && dj < 4) acc[i][dj] = -1e30f;
        float4 r = {acc[i][0], acc[i][1], acc[i][2], acc[i][3]};
        *(float4*)&att[((size_t)(b * 64 + h) * 64 + w) * 128 + g0] = r;
    }
}

__global__ __launch_bounds__(256) void ew_kernel(
        const float* __restrict__ q, const float* __restrict__ k,
        float* __restrict__ att) {
    __shared__ float qs[16][64];
    __shared__ float ks[16][64];
    const int t = threadIdx.x;
    const int h = blockIdx.x, b = blockIdx.y;
    const float* qb2 = q + (size_t)b * 65536 + (size_t)h * 64;
    const float* kb2 = k + (size_t)b * 65536 + (size_t)h * 64;
    #pragma unroll
    for (int i = 0; i < 4; ++i) {
        int e = t + i * 256;
        int c = e >> 6, wl = e & 63;
        qs[c][wl] = qb2[(size_t)c * 4096 + wl];
        ks[c][wl] = kb2[(size_t)c * 4096 + wl];
    }
    __syncthreads();
    const int tt0 = (t & 15) * 4, w0 = (t >> 4) * 4;
    float acc[4][4] = {};
    #pragma unroll
    for (int c = 0; c < 16; ++c) {
        float4 qv = *(const float4*)&qs[c][w0];
        float4 kv = *(const float4*)&ks[c][tt0];
        const float* pq = (const float*)&qv;
        const float* pk = (const float*)&kv;
        #pragma unroll
        for (int i = 0; i < 4; ++i)
            #pragma unroll
            for (int j = 0; j < 4; ++j) acc[i][j] += pq[i] * pk[j];
    }
    #pragma unroll
    for (int i = 0; i < 4; ++i) {
        float4 r = {acc[i][0], acc[i][1], acc[i][2], acc[i][3]};
        *(float4*)&att[((size_t)(b * 64 + h) * 64 + (w0 + i)) * 128 + 64 + tt0] = r;
    }
}

__global__ __launch_bounds__(128) void softmax_kernel(float* __restrict__ att) {
    const int r = blockIdx.x, t = threadIdx.x;
    float v = att[(size_t)r * 128 + t];
    float m = v;
    #pragma unroll
    for (int off = 32; off >= 1; off >>= 1) m = fmaxf(m, __shfl_xor(m, off));
    __shared__ float s1[2], s2[2];
    const int wid = t >> 6, lane = t & 63;
    if (lane == 0) s1[wid] = m;
    __syncthreads();
    m = fmaxf(s1[0], s1[1]);
    float e = expf(v - m);
    float s = e;
    #pragma unroll
    for (int off = 32; off >= 1; off >>= 1) s += __shfl_xor(s, off);
    if (lane == 0) s2[wid] = s;
    __syncthreads();
    s = s2[0] + s2[1];
    att[(size_t)r * 128 + t] = e / s;
}

__global__ __launch_bounds__(256) void oh_kernel(
        const float* __restrict__ v, const float* __restrict__ att,
        float* __restrict__ ohb) {
    __shared__ float vs2[64][128];
    __shared__ float ah2[64][65];
    const int t = threadIdx.x;
    const int w = blockIdx.x, b = blockIdx.y;
    const float* vbp = v + (size_t)b * 524288 + w;
    #pragma unroll
    for (int i = 0; i < 32; ++i) {
        int e = t + i * 256;
        vs2[e >> 7][e & 127] = vbp[((size_t)(e & 127) * 64 + (e >> 7)) * 64];
    }
    const float* abp = att + ((size_t)b * 4096 + w) * 128;
    #pragma unroll
    for (int i = 0; i < 16; ++i) {
        int e = t + i * 256;
        ah2[e >> 6][e & 63] = abp[(size_t)(e >> 6) * 8192 + (e & 63)];
    }
    __syncthreads();
    const int h0 = (t & 15) * 4, c0 = (t >> 4) * 8;
    float acc[8][4] = {};
    for (int g = 0; g < 64; ++g) {
        float4 va  = *(const float4*)&vs2[g][c0];
        float4 vb4 = *(const float4*)&vs2[g][c0 + 4];
        const float* pa = (const float*)&va;
        const float* pb = (const float*)&vb4;
        float aj[4];
        #pragma unroll
        for (int j = 0; j < 4; ++j) aj[j] = ah2[h0 + j][g];
        #pragma unroll
        for (int j = 0; j < 4; ++j)
            #pragma unroll
            for (int i2 = 0; i2 < 4; ++i2) {
                acc[i2][j]     += pa[i2] * aj[j];
                acc[4 + i2][j] += pb[i2] * aj[j];
            }
    }
    #pragma unroll
    for (int i2 = 0; i2 < 8; ++i2)
        #pragma unroll
        for (int j = 0; j < 4; ++j)
            ohb[((size_t)(b * 128 + c0 + i2) * 64 + (h0 + j)) * 64 + w] = acc[i2][j];
}

__global__ __launch_bounds__(256) void ow_final_kernel(
        const float* __restrict__ v, const float* __restrict__ att,
        const float* __restrict__ ohb, const float* __restrict__ gamma,
        const float* __restrict__ Xin, float* __restrict__ Xout) {
    __shared__ float vs2[64][129];
    __shared__ float aws[64][65];
    const int t = threadIdx.x;
    const int h = blockIdx.x, b = blockIdx.y;
    const float* vbp = v + (size_t)b * 524288 + (size_t)h * 64;
    #pragma unroll
    for (int i = 0; i < 32; ++i) {
        int e = t + i * 256;
        vs2[e & 63][e >> 6] = vbp[(size_t)(e >> 6) * 4096 + (e & 63)];
    }
    const float* abp = att + ((size_t)(b * 64 + h) * 64) * 128 + 64;
    #pragma unroll
    for (int i = 0; i < 16; ++i) {
        int e = t + i * 256;
        aws[e >> 6][e & 63] = abp[(size_t)(e >> 6) * 128 + (e & 63)];
    }
    __syncthreads();
    const int w0 = (t & 15) * 4, c0 = (t >> 4) * 8;
    float acc[8][4] = {};
    for (int tt = 0; tt < 64; ++tt) {
        float vv[8];
        #pragma unroll
        for (int i2 = 0; i2 < 8; ++i2) vv[i2] = vs2[tt][c0 + i2];
        float aw[4];
        #pragma unroll
        for (int j = 0; j < 4; ++j) aw[j] = aws[w0 + j][tt];
        #pragma unroll
        for (int i2 = 0; i2 < 8; ++i2)
            #pragma unroll
            for (int j = 0; j < 4; ++j) acc[i2][j] += vv[i2] * aw[j];
    }
    const float gm = gamma[0];
    #pragma unroll
    for (int i2 = 0; i2 < 8; ++i2) {
        size_t base = ((size_t)(b * 128 + c0 + i2) * 64 + h) * 64 + w0;
        float4 oh4 = *(const float4*)&ohb[base];
        float4 xr  = *(const float4*)&Xin[base];
        const float* po = (const float*)&oh4;
        const float* px = (const float*)&xr;
        float4 r;
        float* pr = (float*)&r;
        #pragma unroll
        for (int j = 0; j < 4; ++j) pr[j] = gm * (acc[i2][j] + po[j]) + px[j];
        *(float4*)&Xout[base] = r;
    }
}

// ---------------- launcher ----------------
extern "C" void kernel_launch(void* const* d_in, const int* in_sizes, int n_in,
                              void* d_out, int out_size, void* d_ws, size_t ws_size,
                              hipStream_t stream) {
    const float* x       = (const float*)d_in[0];
    const float* conva_w = (const float*)d_in[1];
    const float* bn1_g   = (const float*)d_in[2];
    const float* bn1_b   = (const float*)d_in[3];
    const float* bn1_m   = (const float*)d_in[4];
    const float* bn1_v   = (const float*)d_in[5];
    const float* wq      = (const float*)d_in[6];
    const float* bq      = (const float*)d_in[7];
    const float* wk      = (const float*)d_in[8];
    const float* bk      = (const float*)d_in[9];
    const float* wv      = (const float*)d_in[10];
    const float* bv      = (const float*)d_in[11];
    const float* gamma   = (const float*)d_in[12];
    const float* convb_w = (const float*)d_in[13];
    const float* bn2_g   = (const float*)d_in[14];
    const float* bn2_b   = (const float*)d_in[15];
    const float* bn2_m   = (const float*)d_in[16];
    const float* bn2_v   = (const float*)d_in[17];
    const float* bott_w  = (const float*)d_in[18];
    // d_in[19] = recurrence (=2), unrolled on host

    float* ws    = (float*)d_ws;
    float* A     = ws;                  // (8,128,64,64)
    float* Bb    = A     + 4194304;     // (8,128,64,64)
    float* vbuf  = Bb    + 4194304;     // (8,128,64,64)  | also XT_cc region? no: separate below
    float* attb  = vbuf  + 4194304;     // (8,64,64,128)
    float* ohb   = attb  + 4194304;     // (8,128,64,64)
    float* qb    = ohb   + 4194304;     // (8,16,64,64)
    float* kb    = qb    + 524288;
    float* XT_x  = kb    + 524288;      // [8][16][64][64][32] fp32 = 16.78M floats
    float* wqk_t = XT_x  + 16777216;
    float* wv_t  = wqk_t + 4096;
    float* bnsA  = wv_t  + 16384;
    float* bnbA  = bnsA  + 128;
    float* bnsB  = bnbA  + 128;
    float* bnbB  = bnsB  + 128;
    unsigned short* WHa = (unsigned short*)(bnbB + 128);   // 9*128*512
    unsigned short* WLa = WHa + 589824;
    unsigned short* WHb = WLa + 589824;                    // 9*128*128
    unsigned short* WLb = WHb + 147456;
    unsigned short* WHc = WLb + 147456;                    // 9*512*640
    unsigned short* WLc = WHc + 2949120;
    // cc-only buffers reused after cc completes:
    float* XT_cc = vbuf;                // [8][4][64][64][32] = 4.19M floats (vbuf dead after cc)
    float* XT_b  = attb;                // same size (attb dead after cc)
    // end of WLc ≈ 170 MB into d_ws

    prep_bn_kernel<<<1, 256, 0, stream>>>(bn1_g, bn1_b, bn1_m, bn1_v,
                                          bn2_g, bn2_b, bn2_m, bn2_v,
                                          bnsA, bnbA, bnsB, bnbB);
    prep_w_kernel<<<256, 256, 0, stream>>>(conva_w, WHa, WLa, 512, 128);
    prep_w_kernel<<<64, 256, 0, stream>>>(convb_w, WHb, WLb, 128, 128);
    prep_w_kernel<<<1280, 256, 0, stream>>>(bott_w, WHc, WLc, 640, 512);
    prep_qkv_kernel<<<80, 256, 0, stream>>>(wq, wk, wv, wqk_t, wv_t);

    transpose_cl_kernel<<<dim3(16, 8, 16), 256, 0, stream>>>(x, XT_x, 16);

    conv3x3_mfma_kernel<16, 128, 0, 16><<<dim3(32, 8, 2), 256, 0, stream>>>(
        XT_x, nullptr, WHa, WLa, bnsA, bnbA, A);

    float* Xi = A;
    float* Xo = Bb;
    for (int it = 0; it < 2; ++it) {
        qk_kernel<<<dim3(64, 8), 256, 0, stream>>>(Xi, wqk_t, bq, bk, qb, kb);
        v_kernel<<<dim3(64, 8), 256, 0, stream>>>(Xi, wv_t, bv, vbuf);
        eh_kernel<<<dim3(64, 8), 256, 0, stream>>>(qb, kb, attb);
        ew_kernel<<<dim3(64, 8), 256, 0, stream>>>(qb, kb, attb);
        softmax_kernel<<<32768, 128, 0, stream>>>(attb);
        oh_kernel<<<dim3(64, 8), 256, 0, stream>>>(vbuf, attb, ohb);
        ow_final_kernel<<<dim3(64, 8), 256, 0, stream>>>(vbuf, attb, ohb, gamma, Xi, Xo);
        float* tmp = Xi; Xi = Xo; Xo = tmp;
    }
    // Xi == A holds cc output

    transpose_cl_kernel<<<dim3(16, 8, 4), 256, 0, stream>>>(Xi, XT_cc, 4);
    conv3x3_mfma_kernel<4, 128, 0, 4><<<dim3(32, 8, 2), 256, 0, stream>>>(
        XT_cc, nullptr, WHb, WLb, bnsB, bnbB, Bb);

    transpose_cl_kernel<<<dim3(16, 8, 4), 256, 0, stream>>>(Bb, XT_b, 4);
    conv3x3_mfma_kernel<20, 512, 1, 16><<<dim3(32, 8, 8), 256, 0, stream>>>(
        XT_x, XT_b, WHc, WLc, nullptr, nullptr, (float*)d_out);
}